// Round 8
// baseline (58.155 us; speedup 1.0000x reference)
//
#include <hip/hip_runtime.h>
#include <math.h>

#define HDIM 1024
#define VDIM 50257
#define LDIM 512

// ws float offsets (all 16B-aligned)
#define WS_ATTLOG 0      // [0,512)       attention logits
#define WS_CTXP   512    // [512,8704)    ctx partials [8][1024] (plain stores)
#define WS_X      8704   // [8704,9728)   GRU input x
#define WS_GH     9728   // [9728,12800)  gh = h@W_hh.T + b_hh
#define WS_HNEW   12800  // [12800,13824) h_new
#define WS_BUCK   13824  // [13824,15872) 128 exp-sum buckets, stride 16 (1/cacheline)

__device__ __forceinline__ float waveSum(float v) {
#pragma unroll
    for (int o = 32; o; o >>= 1) v += __shfl_down(v, o, 64);
    return v;
}

// K1: attn logits (blocks 0..127, 4 rows ea) + gh rows (blocks 128..511, 8 rows ea);
//     block 0 zeros buckets.
__global__ __launch_bounds__(256) void k1(const int* __restrict__ idx_p,
                                          const float* __restrict__ hidden,
                                          const float* __restrict__ emb,
                                          const float* __restrict__ attn_W,
                                          const float* __restrict__ attn_b,
                                          const float* __restrict__ W_hh,
                                          const float* __restrict__ b_hh,
                                          float* __restrict__ ws) {
    const int blk = blockIdx.x, t = threadIdx.x;
    const int wid = t >> 6, lane = t & 63;
    if (blk == 0) {
#pragma unroll
        for (int r = 0; r < 8; ++r) ws[WS_BUCK + r * 256 + t] = 0.f;
    }
    const float4* h4 = (const float4*)hidden;
    if (blk < 128) {
        const float4* e4 = (const float4*)(emb + (size_t)idx_p[0] * HDIM);
        int row = blk * 4 + wid;                        // 0..511
        const float4* w4 = (const float4*)(attn_W + (size_t)row * 2 * HDIM);
        float acc = 0.f;
#pragma unroll
        for (int k = 0; k < 8; ++k) {
            int c = lane + 64 * k;                      // float4 chunk 0..511
            float4 w = w4[c];
            float4 x = (c < 256) ? e4[c] : h4[c - 256];
            acc += w.x * x.x + w.y * x.y + w.z * x.z + w.w * x.w;
        }
        acc = waveSum(acc);
        if (lane == 0) ws[WS_ATTLOG + row] = acc + attn_b[row];
    } else {
        int k0 = (blk - 128) * 8 + wid * 2;             // 0..3070, 2 rows per wave
        const float4* wa = (const float4*)(W_hh + (size_t)k0 * HDIM);
        const float4* wb = (const float4*)(W_hh + (size_t)(k0 + 1) * HDIM);
        float acc0 = 0.f, acc1 = 0.f;
#pragma unroll
        for (int q = 0; q < 4; ++q) {
            int c = lane + 64 * q;
            float4 x = h4[c];
            float4 a = wa[c], b = wb[c];
            acc0 += a.x * x.x + a.y * x.y + a.z * x.z + a.w * x.w;
            acc1 += b.x * x.x + b.y * x.y + b.z * x.z + b.w * x.w;
        }
        acc0 = waveSum(acc0); acc1 = waveSum(acc1);
        if (lane == 0) {
            ws[WS_GH + k0]     = acc0 + b_hh[k0];
            ws[WS_GH + k0 + 1] = acc1 + b_hh[k0 + 1];
        }
    }
}

// K2: redundant softmax(512) per block; blocks 0..31: ctx partial (64 L-rows x 256 h,
//     plain store); block 32: attention-weights output. No atomics.
__global__ __launch_bounds__(256) void k2(const float* __restrict__ enc,
                                          float* __restrict__ ws,
                                          float* __restrict__ out) {
    __shared__ float sred[4];
    __shared__ float sW[512];
    const int blk = blockIdx.x, t = threadIdx.x;
    const int wid = t >> 6, lane = t & 63;
    float v0 = ws[WS_ATTLOG + t], v1 = ws[WS_ATTLOG + 256 + t];
    float m = fmaxf(v0, v1);
#pragma unroll
    for (int o = 32; o; o >>= 1) m = fmaxf(m, __shfl_down(m, o, 64));
    if (lane == 0) sred[wid] = m;
    __syncthreads();
    m = fmaxf(fmaxf(sred[0], sred[1]), fmaxf(sred[2], sred[3]));
    __syncthreads();
    float e0 = expf(v0 - m), e1 = expf(v1 - m);
    float s = waveSum(e0 + e1);
    if (lane == 0) sred[wid] = s;
    __syncthreads();
    s = sred[0] + sred[1] + sred[2] + sred[3];
    float inv = 1.f / s;
    sW[t] = e0 * inv; sW[256 + t] = e1 * inv;
    __syncthreads();
    if (blk == 32) {
        out[VDIM + HDIM + t] = sW[t];
        out[VDIM + HDIM + 256 + t] = sW[256 + t];
    } else {
        int lc = blk & 7, hb = blk >> 3;                // 8 L-chunks x 4 H-chunks
        int h = hb * 256 + t;
        int l0 = lc * 64;
        float acc = 0.f;
#pragma unroll 8
        for (int j = 0; j < 64; ++j)
            acc += sW[l0 + j] * enc[(size_t)(l0 + j) * HDIM + h];
        ws[WS_CTXP + lc * HDIM + h] = acc;              // plain store
    }
}

// K3: sum 8 ctx partials into LDS, then x[j] = relu(dot(cat(emb,ctx), comb_W[j]) + b)
__global__ __launch_bounds__(256) void k3(const int* __restrict__ idx_p,
                                          const float* __restrict__ emb,
                                          const float* __restrict__ comb_W,
                                          const float* __restrict__ comb_b,
                                          float* __restrict__ ws) {
    __shared__ __align__(16) float sctx[1024];
    const int t = threadIdx.x, wid = t >> 6, lane = t & 63;
    {   // thread t sums partials for float4 chunk t (h = 4t..4t+3)
        const float4* p4 = (const float4*)(ws + WS_CTXP);
        float4 a = p4[t];
#pragma unroll
        for (int p = 1; p < 8; ++p) {
            float4 b = p4[p * 256 + t];
            a.x += b.x; a.y += b.y; a.z += b.z; a.w += b.w;
        }
        ((float4*)sctx)[t] = a;
    }
    __syncthreads();
    int j = blockIdx.x * 4 + wid;                       // 0..1023
    const float4* w4 = (const float4*)(comb_W + (size_t)j * 2 * HDIM);
    const float4* e4 = (const float4*)(emb + (size_t)idx_p[0] * HDIM);
    const float4* c4 = (const float4*)sctx;
    float acc = 0.f;
#pragma unroll
    for (int k = 0; k < 8; ++k) {
        int c = lane + 64 * k;
        float4 w = w4[c];
        float4 x = (c < 256) ? e4[c] : c4[c - 256];
        acc += w.x * x.x + w.y * x.y + w.z * x.z + w.w * x.w;
    }
    acc = waveSum(acc);
    if (lane == 0) ws[WS_X + j] = fmaxf(acc + comb_b[j], 0.f);
}

// K4: gi + GRU gate, one h-index per 192-thread block (3 waves = 3 gate rows).
__global__ __launch_bounds__(192) void k4(const float* __restrict__ hidden,
                                          const float* __restrict__ W_ih,
                                          const float* __restrict__ b_ih,
                                          float* __restrict__ ws,
                                          float* __restrict__ out) {
    __shared__ float sg[3];
    const int i = blockIdx.x;                           // h index 0..1023
    const int t = threadIdx.x, r = t >> 6, lane = t & 63;
    const float4* w4 = (const float4*)(W_ih + (size_t)(r * HDIM + i) * HDIM);
    const float4* x4 = (const float4*)(ws + WS_X);
    float acc = 0.f;
#pragma unroll
    for (int q = 0; q < 4; ++q) {
        int c = lane + 64 * q;
        float4 w = w4[c]; float4 x = x4[c];
        acc += w.x * x.x + w.y * x.y + w.z * x.z + w.w * x.w;
    }
    acc = waveSum(acc);
    if (lane == 0) sg[r] = acc + b_ih[r * HDIM + i];
    __syncthreads();
    if (t == 0) {
        float gh_r = ws[WS_GH + i];
        float gh_z = ws[WS_GH + HDIM + i];
        float gh_n = ws[WS_GH + 2 * HDIM + i];
        float r_ = 1.f / (1.f + expf(-(sg[0] + gh_r)));
        float z  = 1.f / (1.f + expf(-(sg[1] + gh_z)));
        float n  = tanhf(sg[2] + r_ * gh_n);
        float hn = (1.f - z) * n + z * hidden[i];
        ws[WS_HNEW + i] = hn;
        out[VDIM + i]   = hn;
    }
}

// K5: V-matvec, 2 consecutive vocab rows per wave (8 loads in flight/lane),
//     h_new staged in LDS; per-block exp partial into cacheline-private bucket.
__global__ __launch_bounds__(256) void k5(const float* __restrict__ out_W,
                                          const float* __restrict__ out_b,
                                          const float* __restrict__ ws,
                                          float* __restrict__ out) {
    __shared__ __align__(16) float sh[1024];
    __shared__ float se[4];
    const int t = threadIdx.x, wid = t >> 6, lane = t & 63;
    ((float4*)sh)[t] = ((const float4*)(ws + WS_HNEW))[t];
    __syncthreads();
    const float4* s4 = (const float4*)sh;
    int v0 = blockIdx.x * 8 + wid * 2;                  // 2 consecutive rows per wave
    int v1 = v0 + 1;
    float epart = 0.f;
    {
        const float4* wa = (const float4*)(out_W + (size_t)v0 * HDIM);
        const float4* wb = (const float4*)(out_W + (size_t)(v1 < VDIM ? v1 : v0) * HDIM);
        float acc0 = 0.f, acc1 = 0.f;
        if (v0 < VDIM) {
#pragma unroll
            for (int q = 0; q < 4; ++q) {
                int c = lane + 64 * q;
                float4 x = s4[c];
                float4 a = wa[c], b = wb[c];
                acc0 += a.x * x.x + a.y * x.y + a.z * x.z + a.w * x.w;
                acc1 += b.x * x.x + b.y * x.y + b.z * x.z + b.w * x.w;
            }
            acc0 = waveSum(acc0); acc1 = waveSum(acc1);
            if (lane == 0) {
                float l0 = acc0 + out_b[v0];
                out[v0] = l0;
                epart = expf(l0);
                if (v1 < VDIM) {
                    float l1 = acc1 + out_b[v1];
                    out[v1] = l1;
                    epart += expf(l1);
                }
            }
        }
    }
    if (lane == 0) se[wid] = epart;
    __syncthreads();
    if (t == 0)
        atomicAdd(const_cast<float*>(ws) + WS_BUCK + (blockIdx.x & 127) * 16,
                  se[0] + se[1] + se[2] + se[3]);
}

// K6: out[i] -= log(sum of 128 strided buckets)
__global__ __launch_bounds__(256) void k6(const float* __restrict__ ws,
                                          float* __restrict__ out) {
    __shared__ float sls[2];
    const int t = threadIdx.x, wid = t >> 6, lane = t & 63;
    if (t < 128) {
        float b = waveSum(ws[WS_BUCK + t * 16]);
        if (lane == 0) sls[wid] = b;
    }
    __syncthreads();
    float ls = logf(sls[0] + sls[1]);
    int i = blockIdx.x * 256 + t;
    if (i < VDIM) out[i] -= ls;
}

extern "C" void kernel_launch(void* const* d_in, const int* in_sizes, int n_in,
                              void* d_out, int out_size, void* d_ws, size_t ws_size,
                              hipStream_t stream) {
    const int*   idx    = (const int*)d_in[0];
    const float* hidden = (const float*)d_in[1];
    const float* enc    = (const float*)d_in[2];
    const float* emb    = (const float*)d_in[3];
    const float* attn_W = (const float*)d_in[4];
    const float* attn_b = (const float*)d_in[5];
    const float* comb_W = (const float*)d_in[6];
    const float* comb_b = (const float*)d_in[7];
    const float* W_ih   = (const float*)d_in[8];
    const float* W_hh   = (const float*)d_in[9];
    const float* b_ih   = (const float*)d_in[10];
    const float* b_hh   = (const float*)d_in[11];
    const float* out_W  = (const float*)d_in[12];
    const float* out_b  = (const float*)d_in[13];

    float* out = (float*)d_out;                 // [V logits][H h_new][L attn_w]
    float* ws  = (float*)d_ws;

    k1<<<512, 256, 0, stream>>>(idx, hidden, emb, attn_W, attn_b, W_hh, b_hh, ws);
    k2<<<33, 256, 0, stream>>>(enc, ws, out);
    k3<<<256, 256, 0, stream>>>(idx, emb, comb_W, comb_b, ws);
    k4<<<1024, 192, 0, stream>>>(hidden, W_ih, b_ih, ws, out);
    k5<<<(VDIM + 7) / 8, 256, 0, stream>>>(out_W, out_b, ws, out);
    k6<<<(VDIM + 255) / 256, 256, 0, stream>>>(ws, out);
}